// Round 9
// baseline (414.544 us; speedup 1.0000x reference)
//
#include <hip/hip_runtime.h>
#include <math.h>

typedef _Float16 f16x8 __attribute__((ext_vector_type(8)));
typedef _Float16 f16x4 __attribute__((ext_vector_type(4)));
typedef float    f32x4 __attribute__((ext_vector_type(4)));

#define FEAT_H 128
#define FEAT_W 352
#define FPIX   (FEAT_H * FEAT_W)   // 45056
#define BEV    320
#define NCELL  (BEV * BEV)         // 102400
#define CH     96
#define PD     322                 // padded spatial dim
#define PPIX   (PD * PD)           // 103684

// ---- workspace layout (float offsets) ----
#define N_PADF    (2 * PPIX * CH / 2)            // 9,953,664 floats
#define OFF_BUFB  0
#define OFF_FS    0                              // featS16: 2*45056*64 f16
#define OFF_FH    2883584                        // featH16: 2*45056*96 f16
#define OFF_WT    (N_PADF)                       // f16 2*9*96*96 = 82,944 floats
#define OFF_HW    (OFF_WT + 82944)               // 64*64 fp32
#define OFF_BASE  (OFF_HW + 4096)                // baseT 192 | wD 64 | flag 1
#define OFF_WD    (OFF_BASE + 192)
#define OFF_FLAG  (OFF_BASE + 256)
#define OFF_BUFA  (OFF_BASE + 512)               // f16 padded conv1 input

// ---------------------------------------------------------------------------
// k_setup: block 0 -> precompute (hW, baseT, wD, flag);
//          blocks 1..648 -> weight prep; blocks 649..659 -> bufA border zero.
// ---------------------------------------------------------------------------
__global__ void k_setup(const float* __restrict__ dw2, const float* __restrict__ sw1,
                        const float* __restrict__ db2, const float* __restrict__ he,
                        const float* __restrict__ sb1, const float* __restrict__ dw1,
                        const float* __restrict__ db1,
                        const float* __restrict__ w1, const float* __restrict__ w2,
                        float* __restrict__ hW, float* __restrict__ baseT,
                        float* __restrict__ wD, float* __restrict__ flagp,
                        _Float16* __restrict__ wt, _Float16* __restrict__ bufA) {
    const int bid = blockIdx.x;
    const int t = threadIdx.x;
    if (bid == 0) {
        for (int idx = t; idx < 64 * 64; idx += 256) {
            int j = idx >> 6, k = idx & 63;
            float s = 0.f;
            for (int c = 0; c < CH; c++) s = fmaf(dw2[j * CH + c], sw1[c * 64 + k], s);
            hW[idx] = s;
        }
        for (int idx = t; idx < 3 * 64; idx += 256) {
            int h = idx >> 6, k = idx & 63;
            float s = sb1[k];
            for (int c = 0; c < CH; c++) s = fmaf(db2[c] + he[h * CH + c], sw1[c * 64 + k], s);
            baseT[idx] = s;
        }
        __syncthreads();
        if (t < 64) {
            float s = 0.f;
            for (int j = 0; j < 64; j++) {
                float w = dw1[j];
                if (w > 0.f) s = fmaf(w, hW[j * 64 + t], s);
            }
            wD[t] = s;
        }
        if (t == 0) {
            float mx = 0.f;
            for (int j = 0; j < 64; j++) mx = fmaxf(mx, fabsf(db1[j]));
            flagp[0] = (mx == 0.f) ? 1.f : 0.f;
        }
    } else if (bid <= 648) {
        int idx = (bid - 1) * 256 + t;              // 0 .. 165887
        int cv = idx / 82944; int r = idx - cv * 82944;
        int tap = r / 9216;   int rr = r - tap * 9216;
        int oc = rr / 96;     int ic = rr - oc * 96;
        const float* src = cv ? w2 : w1;
        wt[idx] = (_Float16)src[(oc * 96 + ic) * 9 + tap];
    } else {
        int idx = (bid - 649) * 256 + t;            // 0 .. 2815 (need 2568)
        if (idx >= 2568) return;
        int img = idx / 1284; int p = idx - img * 1284;
        int row, col;
        if (p < 322)      { row = 0;           col = p; }
        else if (p < 644) { row = 321;         col = p - 322; }
        else if (p < 964) { row = p - 644 + 1; col = 0; }
        else              { row = p - 964 + 1; col = 321; }
        _Float16* q = bufA + ((size_t)(img * PD + row) * PD + col) * CH;
        f16x8 z = {};
        #pragma unroll
        for (int c8 = 0; c8 < 12; ++c8) *(f16x8*)(q + c8 * 8) = z;
    }
}

// ---------------------------------------------------------------------------
// k_feats: featS16[b][pix][64] = f16(feat[b][:][pix] @ sw1)
//          featH16[b][pix][96] = f16(feat[b][:][pix])   (CHW -> HWC transpose)
// ---------------------------------------------------------------------------
__global__ __launch_bounds__(64) void k_feats(const float* __restrict__ feat,
                                              const float* __restrict__ sw1,
                                              _Float16* __restrict__ featS,
                                              _Float16* __restrict__ featH) {
    const int t = threadIdx.x;
    const int pb = blockIdx.x * 64;
    const int b = blockIdx.y;
    __shared__ float ld[CH * 64];
    const float* fp = feat + (size_t)b * CH * FPIX + pb;
    #pragma unroll 8
    for (int c = 0; c < CH; c++) ld[c * 64 + t] = fp[(size_t)c * FPIX + t];
    __syncthreads();

    float acc[64];
    #pragma unroll
    for (int k = 0; k < 64; k++) acc[k] = 0.f;
    for (int c = 0; c < CH; c++) {
        float x = ld[c * 64 + t];
        const float4* wr = (const float4*)(sw1 + c * 64);
        #pragma unroll
        for (int k4 = 0; k4 < 16; k4++) {
            float4 w = wr[k4];
            acc[4 * k4 + 0] = fmaf(x, w.x, acc[4 * k4 + 0]);
            acc[4 * k4 + 1] = fmaf(x, w.y, acc[4 * k4 + 1]);
            acc[4 * k4 + 2] = fmaf(x, w.z, acc[4 * k4 + 2]);
            acc[4 * k4 + 3] = fmaf(x, w.w, acc[4 * k4 + 3]);
        }
    }
    _Float16* opS = featS + ((size_t)b * FPIX + pb + t) * 64;
    #pragma unroll
    for (int k8 = 0; k8 < 8; k8++) {
        f16x8 v;
        #pragma unroll
        for (int e = 0; e < 8; e++) v[e] = (_Float16)acc[k8 * 8 + e];
        *(f16x8*)(opS + k8 * 8) = v;
    }
    _Float16* opH = featH + ((size_t)b * FPIX + pb + t) * 96;
    #pragma unroll
    for (int c8 = 0; c8 < 12; c8++) {
        f16x8 v;
        #pragma unroll
        for (int e = 0; e < 8; e++) v[e] = (_Float16)ld[(c8 * 8 + e) * 64 + t];
        *(f16x8*)(opH + c8 * 8) = v;
    }
}

// ---------------------------------------------------------------------------
// Lift: one thread per BEV cell, all 3 heights in-thread, no LDS/barriers.
// One-pass 96-ch weighted gather (single 192B write per pixel).
// ---------------------------------------------------------------------------
__global__ __launch_bounds__(256, 3) void k_lift(const _Float16* __restrict__ featS,
                                                 const _Float16* __restrict__ featH,
                                                 const float* __restrict__ l2i,
                                                 const float* __restrict__ dw1,
                                                 const float* __restrict__ db1,
                                                 const float* __restrict__ sw2,
                                                 const float* __restrict__ sb2,
                                                 const float* __restrict__ hW,
                                                 const float* __restrict__ baseT,
                                                 const float* __restrict__ wD,
                                                 const float* __restrict__ flagp,
                                                 _Float16* __restrict__ out) {
    const int tid = threadIdx.x;
    const int b = blockIdx.y;
    const int n = blockIdx.x * 256 + tid;
    const int i = n / BEV, j = n % BEV;
    const float px = ((j + 0.5f) / 320.0f) * 102.4f - 51.2f;
    const float py = ((i + 0.5f) / 320.0f) * 102.4f - 51.2f;
    const float* M = l2i + b * 16;
    const float m00 = M[0], m01 = M[1], m02 = M[2], m03 = M[3];
    const float m10 = M[4], m11 = M[5], m12 = M[6], m13 = M[7];
    const float m20 = M[8], m21 = M[9], m22 = M[10], m23 = M[11];

    const _Float16* fSb = featS + (size_t)b * FPIX * 64;
    const _Float16* fHb = featH + (size_t)b * FPIX * 96;

    int   ti[3][4];
    float tw[3][4];
    float logit[3];
    const bool fast = (flagp[0] != 0.f);

    #pragma unroll
    for (int h = 0; h < 3; h++) {
        logit[h] = -INFINITY;
        ti[h][0] = ti[h][1] = ti[h][2] = ti[h][3] = 0;
        tw[h][0] = tw[h][1] = tw[h][2] = tw[h][3] = 0.f;
        const float z = (float)h;
        const float p0 = m03 + m00 * px + m01 * py + m02 * z;
        const float p1 = m13 + m10 * px + m11 * py + m12 * z;
        const float dep = m23 + m20 * px + m21 * py + m22 * z;
        const float dv = fmaxf(dep, 1e-5f);
        const float u = p0 / dv, v = p1 / dv;
        const float gx = (u / 351.0f) * 2.0f - 1.0f;
        const float gy = (v / 127.0f) * 2.0f - 1.0f;
        const bool valid = (dep > 1e-3f) && (fabsf(gx) <= 1.0f) && (fabsf(gy) <= 1.0f);
        if (!valid) continue;

        float xs = (gx + 1.0f) * 0.5f * 351.0f;
        float ys = (gy + 1.0f) * 0.5f * 127.0f;
        float xf = floorf(xs), yf = floorf(ys);
        int x0 = (int)xf, y0 = (int)yf;
        float wx = xs - xf, wy = ys - yf;
        int x1 = (x0 < FEAT_W - 1) ? x0 + 1 : x0;
        int y1 = (y0 < FEAT_H - 1) ? y0 + 1 : y0;
        ti[h][0] = y0 * FEAT_W + x0;  ti[h][1] = y0 * FEAT_W + x1;
        ti[h][2] = y1 * FEAT_W + x0;  ti[h][3] = y1 * FEAT_W + x1;
        const float tw0 = (1.f - wx) * (1.f - wy), tw1 = wx * (1.f - wy);
        const float tw2 = (1.f - wx) * wy,         tw3 = wx * wy;
        tw[h][0] = tw0; tw[h][1] = tw1; tw[h][2] = tw2; tw[h][3] = tw3;

        const float dl = log1pf(fmaxf(dep, 1e-3f));
        const _Float16* q0 = fSb + (size_t)ti[h][0] * 64;
        const _Float16* q1 = fSb + (size_t)ti[h][1] * 64;
        const _Float16* q2 = fSb + (size_t)ti[h][2] * 64;
        const _Float16* q3 = fSb + (size_t)ti[h][3] * 64;
        float lg = sb2[0];
        if (fast) {
            #pragma unroll
            for (int kc = 0; kc < 4; kc++) {
                float hid[16];
                const float4* bs = (const float4*)(baseT + h * 64 + kc * 16);
                const float4* wd = (const float4*)(wD + kc * 16);
                #pragma unroll
                for (int q4 = 0; q4 < 4; q4++) {
                    float4 bv = bs[q4], wv = wd[q4];
                    hid[4 * q4 + 0] = fmaf(dl, wv.x, bv.x);
                    hid[4 * q4 + 1] = fmaf(dl, wv.y, bv.y);
                    hid[4 * q4 + 2] = fmaf(dl, wv.z, bv.z);
                    hid[4 * q4 + 3] = fmaf(dl, wv.w, bv.w);
                }
                f16x8 a0 = *(const f16x8*)(q0 + kc * 16),  a0b = *(const f16x8*)(q0 + kc * 16 + 8);
                f16x8 a1 = *(const f16x8*)(q1 + kc * 16),  a1b = *(const f16x8*)(q1 + kc * 16 + 8);
                f16x8 a2 = *(const f16x8*)(q2 + kc * 16),  a2b = *(const f16x8*)(q2 + kc * 16 + 8);
                f16x8 a3 = *(const f16x8*)(q3 + kc * 16),  a3b = *(const f16x8*)(q3 + kc * 16 + 8);
                #pragma unroll
                for (int e = 0; e < 8; e++) {
                    hid[e]     = fmaf(tw0, (float)a0[e],  fmaf(tw1, (float)a1[e],
                                 fmaf(tw2, (float)a2[e],  fmaf(tw3, (float)a3[e],  hid[e]))));
                    hid[e + 8] = fmaf(tw0, (float)a0b[e], fmaf(tw1, (float)a1b[e],
                                 fmaf(tw2, (float)a2b[e], fmaf(tw3, (float)a3b[e], hid[e + 8]))));
                }
                const float4* s2 = (const float4*)(sw2 + kc * 16);
                #pragma unroll
                for (int q4 = 0; q4 < 4; q4++) {
                    float4 sv = s2[q4];
                    lg = fmaf(fmaxf(hid[4 * q4 + 0], 0.f), sv.x, lg);
                    lg = fmaf(fmaxf(hid[4 * q4 + 1], 0.f), sv.y, lg);
                    lg = fmaf(fmaxf(hid[4 * q4 + 2], 0.f), sv.z, lg);
                    lg = fmaf(fmaxf(hid[4 * q4 + 3], 0.f), sv.w, lg);
                }
            }
        } else {
            #pragma unroll
            for (int kc = 0; kc < 4; kc++) {
                float hid[16];
                const float4* bs = (const float4*)(baseT + h * 64 + kc * 16);
                #pragma unroll
                for (int q4 = 0; q4 < 4; q4++) {
                    float4 bv = bs[q4];
                    hid[4 * q4 + 0] = bv.x; hid[4 * q4 + 1] = bv.y;
                    hid[4 * q4 + 2] = bv.z; hid[4 * q4 + 3] = bv.w;
                }
                f16x8 a0 = *(const f16x8*)(q0 + kc * 16),  a0b = *(const f16x8*)(q0 + kc * 16 + 8);
                f16x8 a1 = *(const f16x8*)(q1 + kc * 16),  a1b = *(const f16x8*)(q1 + kc * 16 + 8);
                f16x8 a2 = *(const f16x8*)(q2 + kc * 16),  a2b = *(const f16x8*)(q2 + kc * 16 + 8);
                f16x8 a3 = *(const f16x8*)(q3 + kc * 16),  a3b = *(const f16x8*)(q3 + kc * 16 + 8);
                #pragma unroll
                for (int e = 0; e < 8; e++) {
                    hid[e]     = fmaf(tw0, (float)a0[e],  fmaf(tw1, (float)a1[e],
                                 fmaf(tw2, (float)a2[e],  fmaf(tw3, (float)a3[e],  hid[e]))));
                    hid[e + 8] = fmaf(tw0, (float)a0b[e], fmaf(tw1, (float)a1b[e],
                                 fmaf(tw2, (float)a2b[e], fmaf(tw3, (float)a3b[e], hid[e + 8]))));
                }
                for (int jj = 0; jj < 64; jj++) {
                    float hd = fmaxf(fmaf(dl, dw1[jj], db1[jj]), 0.f);
                    const float4* hr = (const float4*)(hW + jj * 64 + kc * 16);
                    #pragma unroll
                    for (int q4 = 0; q4 < 4; q4++) {
                        float4 wv = hr[q4];
                        hid[4 * q4 + 0] = fmaf(hd, wv.x, hid[4 * q4 + 0]);
                        hid[4 * q4 + 1] = fmaf(hd, wv.y, hid[4 * q4 + 1]);
                        hid[4 * q4 + 2] = fmaf(hd, wv.z, hid[4 * q4 + 2]);
                        hid[4 * q4 + 3] = fmaf(hd, wv.w, hid[4 * q4 + 3]);
                    }
                }
                const float4* s2 = (const float4*)(sw2 + kc * 16);
                #pragma unroll
                for (int q4 = 0; q4 < 4; q4++) {
                    float4 sv = s2[q4];
                    lg = fmaf(fmaxf(hid[4 * q4 + 0], 0.f), sv.x, lg);
                    lg = fmaf(fmaxf(hid[4 * q4 + 1], 0.f), sv.y, lg);
                    lg = fmaf(fmaxf(hid[4 * q4 + 2], 0.f), sv.z, lg);
                    lg = fmaf(fmaxf(hid[4 * q4 + 3], 0.f), sv.w, lg);
                }
            }
        }
        logit[h] = lg;
    }

    const float mx = fmaxf(logit[0], fmaxf(logit[1], logit[2]));
    float wh[3] = {0.f, 0.f, 0.f};
    if (mx > -INFINITY) {
        float e0 = (logit[0] > -INFINITY) ? expf(logit[0] - mx) : 0.f;
        float e1 = (logit[1] > -INFINITY) ? expf(logit[1] - mx) : 0.f;
        float e2 = (logit[2] > -INFINITY) ? expf(logit[2] - mx) : 0.f;
        const float inv = 1.0f / (e0 + e1 + e2);
        wh[0] = e0 * inv; wh[1] = e1 * inv; wh[2] = e2 * inv;
    }

    // one-pass weighted 96-ch gather
    float acc[96];
    #pragma unroll
    for (int k = 0; k < 96; k++) acc[k] = 0.f;
    #pragma unroll
    for (int h = 0; h < 3; h++) {
        if (wh[h] > 0.f) {
            const float c0 = wh[h] * tw[h][0], c1 = wh[h] * tw[h][1];
            const float c2 = wh[h] * tw[h][2], c3 = wh[h] * tw[h][3];
            const _Float16* g0 = fHb + (size_t)ti[h][0] * 96;
            const _Float16* g1 = fHb + (size_t)ti[h][1] * 96;
            const _Float16* g2 = fHb + (size_t)ti[h][2] * 96;
            const _Float16* g3 = fHb + (size_t)ti[h][3] * 96;
            #pragma unroll
            for (int c8 = 0; c8 < 12; c8++) {
                f16x8 v0 = *(const f16x8*)(g0 + c8 * 8);
                f16x8 v1 = *(const f16x8*)(g1 + c8 * 8);
                f16x8 v2 = *(const f16x8*)(g2 + c8 * 8);
                f16x8 v3 = *(const f16x8*)(g3 + c8 * 8);
                #pragma unroll
                for (int e = 0; e < 8; e++)
                    acc[c8 * 8 + e] += fmaf(c0, (float)v0[e], fmaf(c1, (float)v1[e],
                                       fmaf(c2, (float)v2[e], c3 * (float)v3[e])));
            }
        }
    }
    _Float16* op = out + ((size_t)(b * PD + i + 1) * PD + (j + 1)) * CH;
    #pragma unroll
    for (int c8 = 0; c8 < 12; ++c8) {
        f16x8 v;
        #pragma unroll
        for (int e = 0; e < 8; e++) v[e] = (_Float16)acc[c8 * 8 + e];
        *(f16x8*)(op + c8 * 8) = v;
    }
}

// ---------------------------------------------------------------------------
// Conv 3x3 + BN + ReLU, f16 MFMA implicit GEMM, BOTH operands from LDS in
// K-major chunk layouts (16B lane stride -> 2-way bank aliasing = free).
// Block: 4 rows x 32 cols, 4 waves; wave = 1 row = 2 pixel-tiles x 6 oc-tiles.
// Weights staged per-tap into a double-buffered LDS region (18.4 KB/tap);
// next tap's weights prefetched into registers during compute. One barrier
// per tap. LDS total 76 KB -> 2 blocks/CU. No global loads in the K-loop.
// ---------------------------------------------------------------------------
template<int MODE>
__global__ __launch_bounds__(256, 2) void k_conv_mfma(
        const _Float16* __restrict__ in, const _Float16* __restrict__ wt,
        const float* __restrict__ bng, const float* __restrict__ bnb,
        const float* __restrict__ bnm, const float* __restrict__ bnv,
        void* __restrict__ outv) {
    __shared__ _Float16 sP[6 * 12 * 34 * 8];   // pixels [row][kcq][col][8ch] = 39,168 B
    __shared__ _Float16 sW[2 * 1152 * 8];      // weights dbuf [kcq][oc][8ch] = 36,864 B
    const int tid = threadIdx.x;
    const int w = tid >> 6, lane = tid & 63, q = lane >> 4, n = lane & 15;
    const int x0 = blockIdx.x * 32, y0 = blockIdx.y * 4, b = blockIdx.z;
    const _Float16* inb = in + (size_t)b * PPIX * CH;

    // stage pixel halo 6x34, K-major: dest ((row*12 + c8)*34 + col)*8
    for (int idx = tid; idx < 6 * 34 * 12; idx += 256) {
        int pix = idx / 12, c8 = idx - pix * 12;
        int rr = pix / 34, cc = pix - rr * 34;
        *(f16x8*)(&sP[((rr * 12 + c8) * 34 + cc) * 8]) =
            *(const f16x8*)(inb + ((size_t)(y0 + rr) * PD + (x0 + cc)) * CH + c8 * 8);
    }
    // stage tap 0 weights: chunk c = kcq*96 + oc; src = wt + oc*96 + kcq*8
    #pragma unroll
    for (int k = 0; k < 5; ++k) {
        int c = tid + k * 256;
        if (c < 1152) {
            int oc = c % 96, kcq = c / 96;
            *(f16x8*)(&sW[c * 8]) = *(const f16x8*)(wt + oc * 96 + kcq * 8);
        }
    }
    __syncthreads();

    f32x4 acc[6][2];
    #pragma unroll
    for (int ot = 0; ot < 6; ot++)
        #pragma unroll
        for (int mt = 0; mt < 2; mt++) acc[ot][mt] = (f32x4){0.f, 0.f, 0.f, 0.f};

    #pragma unroll
    for (int tap = 0; tap < 9; ++tap) {
        // prefetch next tap's weights into registers
        f16x8 stg[5];
        if (tap < 8) {
            #pragma unroll
            for (int k = 0; k < 5; ++k) {
                int c = tid + k * 256;
                if (c < 1152) {
                    int oc = c % 96, kcq = c / 96;
                    stg[k] = *(const f16x8*)(wt + (tap + 1) * 9216 + oc * 96 + kcq * 8);
                }
            }
        }
        const int r = tap / 3, s = tap % 3;
        const _Float16* wb = sW + (tap & 1) * 9216;
        #pragma unroll
        for (int kc = 0; kc < 3; ++kc) {
            const int kcq = kc * 4 + q;
            f16x8 bf[6], af[2];
            #pragma unroll
            for (int ot = 0; ot < 6; ++ot)
                bf[ot] = *(const f16x8*)(wb + (kcq * 96 + ot * 16 + n) * 8);
            #pragma unroll
            for (int mt = 0; mt < 2; ++mt)
                af[mt] = *(const f16x8*)(&sP[(((w + r) * 12 + kcq) * 34
                                              + (mt * 16 + s + n)) * 8]);
            #pragma unroll
            for (int ot = 0; ot < 6; ++ot)
                #pragma unroll
                for (int mt = 0; mt < 2; ++mt)
                    acc[ot][mt] = __builtin_amdgcn_mfma_f32_16x16x32_f16(
                                      bf[ot], af[mt], acc[ot][mt], 0, 0, 0);
        }
        if (tap < 8) {
            _Float16* wdst = sW + ((tap + 1) & 1) * 9216;
            #pragma unroll
            for (int k = 0; k < 5; ++k) {
                int c = tid + k * 256;
                if (c < 1152) *(f16x8*)(&wdst[c * 8]) = stg[k];
            }
        }
        __syncthreads();
    }

    float scv[6][4], shv[6][4];
    #pragma unroll
    for (int ot = 0; ot < 6; ot++)
        #pragma unroll
        for (int rg = 0; rg < 4; rg++) {
            int oc = ot * 16 + q * 4 + rg;
            scv[ot][rg] = bng[oc] * rsqrtf(bnv[oc] + 1e-3f);
            shv[ot][rg] = fmaf(-bnm[oc], scv[ot][rg], bnb[oc]);
        }

    if (MODE == 0) {
        _Float16* outb = (_Float16*)outv + (size_t)b * PPIX * CH;
        const int orow = y0 + w + 1;
        #pragma unroll
        for (int mt = 0; mt < 2; mt++) {
            const int ocol = x0 + mt * 16 + n + 1;
            _Float16* op = outb + ((size_t)orow * PD + ocol) * CH + q * 4;
            #pragma unroll
            for (int ot = 0; ot < 6; ot++) {
                f16x4 pv;
                #pragma unroll
                for (int rg = 0; rg < 4; rg++)
                    pv[rg] = (_Float16)fmaxf(fmaf(acc[ot][mt][rg], scv[ot][rg], shv[ot][rg]), 0.f);
                *(f16x4*)(op + ot * 16) = pv;
            }
        }
        // ---- fold border zeroing: edge blocks clear adjacent border pixels ----
        const int bx = blockIdx.x, by = blockIdx.y;
        f16x8 zz = {};
        if (bx == 0 && tid < 4) {
            _Float16* p = outb + ((size_t)(y0 + 1 + tid) * PD + 0) * CH;
            #pragma unroll
            for (int c8 = 0; c8 < 12; ++c8) *(f16x8*)(p + c8 * 8) = zz;
        }
        if (bx == 9 && tid >= 8 && tid < 12) {
            _Float16* p = outb + ((size_t)(y0 + 1 + (tid - 8)) * PD + 321) * CH;
            #pragma unroll
            for (int c8 = 0; c8 < 12; ++c8) *(f16x8*)(p + c8 * 8) = zz;
        }
        if (by == 0 && tid >= 16 && tid < 48) {
            _Float16* p = outb + ((size_t)0 * PD + (x0 + 1 + (tid - 16))) * CH;
            #pragma unroll
            for (int c8 = 0; c8 < 12; ++c8) *(f16x8*)(p + c8 * 8) = zz;
        }
        if (by == 79 && tid >= 48 && tid < 80) {
            _Float16* p = outb + ((size_t)321 * PD + (x0 + 1 + (tid - 48))) * CH;
            #pragma unroll
            for (int c8 = 0; c8 < 12; ++c8) *(f16x8*)(p + c8 * 8) = zz;
        }
        if (tid == 80) {
            _Float16* p = 0;
            if (bx == 0 && by == 0)       p = outb + ((size_t)0 * PD + 0) * CH;
            else if (bx == 9 && by == 0)  p = outb + ((size_t)0 * PD + 321) * CH;
            else if (bx == 0 && by == 79) p = outb + ((size_t)321 * PD + 0) * CH;
            else if (bx == 9 && by == 79) p = outb + ((size_t)321 * PD + 321) * CH;
            if (p) {
                #pragma unroll
                for (int c8 = 0; c8 < 12; ++c8) *(f16x8*)(p + c8 * 8) = zz;
            }
        }
    } else {
        float* outb = (float*)outv + (size_t)b * CH * NCELL;
        const int prow = y0 + w;
        #pragma unroll
        for (int mt = 0; mt < 2; mt++) {
            const int pcol = x0 + mt * 16 + n;
            #pragma unroll
            for (int ot = 0; ot < 6; ot++)
                #pragma unroll
                for (int rg = 0; rg < 4; rg++) {
                    int oc = ot * 16 + q * 4 + rg;
                    outb[(size_t)oc * NCELL + prow * BEV + pcol] =
                        fmaxf(fmaf(acc[ot][mt][rg], scv[ot][rg], shv[ot][rg]), 0.f);
                }
        }
    }
}

// ---------------------------------------------------------------------------
extern "C" void kernel_launch(void* const* d_in, const int* in_sizes, int n_in,
                              void* d_out, int out_size, void* d_ws, size_t ws_size,
                              hipStream_t stream) {
    const float* feat = (const float*)d_in[0];
    const float* l2i  = (const float*)d_in[1];
    const float* he   = (const float*)d_in[2];
    const float* dw1  = (const float*)d_in[3];
    const float* db1  = (const float*)d_in[4];
    const float* dw2  = (const float*)d_in[5];
    const float* db2  = (const float*)d_in[6];
    const float* sw1  = (const float*)d_in[7];
    const float* sb1  = (const float*)d_in[8];
    const float* sw2  = (const float*)d_in[9];
    const float* sb2  = (const float*)d_in[10];
    const float* c1w  = (const float*)d_in[11];
    const float* bn1g = (const float*)d_in[12];
    const float* bn1b = (const float*)d_in[13];
    const float* bn1m = (const float*)d_in[14];
    const float* bn1v = (const float*)d_in[15];
    const float* c2w  = (const float*)d_in[16];
    const float* bn2g = (const float*)d_in[17];
    const float* bn2b = (const float*)d_in[18];
    const float* bn2m = (const float*)d_in[19];
    const float* bn2v = (const float*)d_in[20];

    float* ws = (float*)d_ws;
    _Float16*  bufB   = (_Float16*)(ws + OFF_BUFB);
    _Float16*  featS  = (_Float16*)(ws + OFF_FS);   // aliases bufB (dead before conv1)
    _Float16*  featH  = (_Float16*)(ws + OFF_FH);   // aliases bufB (dead before conv1)
    _Float16*  wtp    = (_Float16*)(ws + OFF_WT);
    float*     hW     = ws + OFF_HW;
    float*     baseT  = ws + OFF_BASE;
    float*     wD     = ws + OFF_WD;
    float*     flagp  = ws + OFF_FLAG;
    _Float16*  bufA   = (_Float16*)(ws + OFF_BUFA);
    _Float16*  wt1    = wtp;
    _Float16*  wt2    = wtp + 82944;

    hipLaunchKernelGGL(k_setup, dim3(660), dim3(256), 0, stream,
                       dw2, sw1, db2, he, sb1, dw1, db1, c1w, c2w,
                       hW, baseT, wD, flagp, wtp, bufA);
    hipLaunchKernelGGL(k_feats, dim3(FPIX / 64, 2), dim3(64), 0, stream,
                       feat, sw1, featS, featH);
    hipLaunchKernelGGL(k_lift, dim3(NCELL / 256, 2), dim3(256), 0, stream,
                       featS, featH, l2i, dw1, db1, sw2, sb2, hW, baseT, wD, flagp, bufA);
    // conv<0> zeroes bufB's border itself (edge blocks), so no k_border launch.
    hipLaunchKernelGGL((k_conv_mfma<0>), dim3(10, 80, 2), dim3(256), 0, stream,
                       bufA, wt1, bn1g, bn1b, bn1m, bn1v, (void*)bufB);
    hipLaunchKernelGGL((k_conv_mfma<1>), dim3(10, 80, 2), dim3(256), 0, stream,
                       bufB, wt2, bn2g, bn2b, bn2m, bn2v, d_out);
}

// Round 10
// 381.662 us; speedup vs baseline: 1.0862x; 1.0862x over previous
//
#include <hip/hip_runtime.h>
#include <math.h>

typedef _Float16 f16x8 __attribute__((ext_vector_type(8)));
typedef _Float16 f16x4 __attribute__((ext_vector_type(4)));
typedef float    f32x4 __attribute__((ext_vector_type(4)));

#define FEAT_H 128
#define FEAT_W 352
#define FPIX   (FEAT_H * FEAT_W)   // 45056
#define BEV    320
#define NCELL  (BEV * BEV)         // 102400
#define CH     96
#define PD     322                 // padded spatial dim
#define PPIX   (PD * PD)           // 103684

// ---- workspace layout (float offsets) ----
#define N_PADF    (2 * PPIX * CH / 2)            // 9,953,664 floats
#define OFF_BUFB  0
#define OFF_FS    0                              // featS16: 2*45056*64 f16
#define OFF_FH    2883584                        // featH16: 2*45056*96 f16
#define OFF_WT    (N_PADF)                       // f16 2*9*96*96 = 82,944 floats
#define OFF_HW    (OFF_WT + 82944)               // 64*64 fp32
#define OFF_BASE  (OFF_HW + 4096)                // baseT 192 | wD 64 | flag 1
#define OFF_WD    (OFF_BASE + 192)
#define OFF_FLAG  (OFF_BASE + 256)
#define OFF_BUFA  (OFF_BASE + 512)               // f16 padded conv1 input

// ---------------------------------------------------------------------------
// k_setup: block 0 -> precompute (hW, baseT, wD, flag);
//          blocks 1..648 -> weight prep; blocks 649..659 -> bufA border zero.
// ---------------------------------------------------------------------------
__global__ void k_setup(const float* __restrict__ dw2, const float* __restrict__ sw1,
                        const float* __restrict__ db2, const float* __restrict__ he,
                        const float* __restrict__ sb1, const float* __restrict__ dw1,
                        const float* __restrict__ db1,
                        const float* __restrict__ w1, const float* __restrict__ w2,
                        float* __restrict__ hW, float* __restrict__ baseT,
                        float* __restrict__ wD, float* __restrict__ flagp,
                        _Float16* __restrict__ wt, _Float16* __restrict__ bufA) {
    const int bid = blockIdx.x;
    const int t = threadIdx.x;
    if (bid == 0) {
        for (int idx = t; idx < 64 * 64; idx += 256) {
            int j = idx >> 6, k = idx & 63;
            float s = 0.f;
            for (int c = 0; c < CH; c++) s = fmaf(dw2[j * CH + c], sw1[c * 64 + k], s);
            hW[idx] = s;
        }
        for (int idx = t; idx < 3 * 64; idx += 256) {
            int h = idx >> 6, k = idx & 63;
            float s = sb1[k];
            for (int c = 0; c < CH; c++) s = fmaf(db2[c] + he[h * CH + c], sw1[c * 64 + k], s);
            baseT[idx] = s;
        }
        __syncthreads();
        if (t < 64) {
            float s = 0.f;
            for (int j = 0; j < 64; j++) {
                float w = dw1[j];
                if (w > 0.f) s = fmaf(w, hW[j * 64 + t], s);
            }
            wD[t] = s;
        }
        if (t == 0) {
            float mx = 0.f;
            for (int j = 0; j < 64; j++) mx = fmaxf(mx, fabsf(db1[j]));
            flagp[0] = (mx == 0.f) ? 1.f : 0.f;
        }
    } else if (bid <= 648) {
        int idx = (bid - 1) * 256 + t;              // 0 .. 165887
        int cv = idx / 82944; int r = idx - cv * 82944;
        int tap = r / 9216;   int rr = r - tap * 9216;
        int oc = rr / 96;     int ic = rr - oc * 96;
        const float* src = cv ? w2 : w1;
        wt[idx] = (_Float16)src[(oc * 96 + ic) * 9 + tap];
    } else {
        int idx = (bid - 649) * 256 + t;            // 0 .. 2815 (need 2568)
        if (idx >= 2568) return;
        int img = idx / 1284; int p = idx - img * 1284;
        int row, col;
        if (p < 322)      { row = 0;           col = p; }
        else if (p < 644) { row = 321;         col = p - 322; }
        else if (p < 964) { row = p - 644 + 1; col = 0; }
        else              { row = p - 964 + 1; col = 321; }
        _Float16* q = bufA + ((size_t)(img * PD + row) * PD + col) * CH;
        f16x8 z = {};
        #pragma unroll
        for (int c8 = 0; c8 < 12; ++c8) *(f16x8*)(q + c8 * 8) = z;
    }
}

// ---------------------------------------------------------------------------
// Zero the 1-pixel border of a padded f16 HWC buffer [2][322][322][96]
// ---------------------------------------------------------------------------
__global__ void k_border(_Float16* __restrict__ buf) {
    int idx = blockIdx.x * 256 + threadIdx.x;       // 2*1284 = 2568 border pixels
    if (idx >= 2568) return;
    int img = idx / 1284; int p = idx - img * 1284;
    int row, col;
    if (p < 322)      { row = 0;           col = p; }
    else if (p < 644) { row = 321;         col = p - 322; }
    else if (p < 964) { row = p - 644 + 1; col = 0; }
    else              { row = p - 964 + 1; col = 321; }
    _Float16* q = buf + ((size_t)(img * PD + row) * PD + col) * CH;
    f16x8 z = {};
    #pragma unroll
    for (int c8 = 0; c8 < 12; ++c8) *(f16x8*)(q + c8 * 8) = z;
}

// ---------------------------------------------------------------------------
// k_feats: featS16[b][pix][64] = f16(feat[b][:][pix] @ sw1)
//          featH16[b][pix][96] = f16(feat[b][:][pix])   (CHW -> HWC transpose)
// ---------------------------------------------------------------------------
__global__ __launch_bounds__(64) void k_feats(const float* __restrict__ feat,
                                              const float* __restrict__ sw1,
                                              _Float16* __restrict__ featS,
                                              _Float16* __restrict__ featH) {
    const int t = threadIdx.x;
    const int pb = blockIdx.x * 64;
    const int b = blockIdx.y;
    __shared__ float ld[CH * 64];
    const float* fp = feat + (size_t)b * CH * FPIX + pb;
    #pragma unroll 8
    for (int c = 0; c < CH; c++) ld[c * 64 + t] = fp[(size_t)c * FPIX + t];
    __syncthreads();

    float acc[64];
    #pragma unroll
    for (int k = 0; k < 64; k++) acc[k] = 0.f;
    for (int c = 0; c < CH; c++) {
        float x = ld[c * 64 + t];
        const float4* wr = (const float4*)(sw1 + c * 64);
        #pragma unroll
        for (int k4 = 0; k4 < 16; k4++) {
            float4 w = wr[k4];
            acc[4 * k4 + 0] = fmaf(x, w.x, acc[4 * k4 + 0]);
            acc[4 * k4 + 1] = fmaf(x, w.y, acc[4 * k4 + 1]);
            acc[4 * k4 + 2] = fmaf(x, w.z, acc[4 * k4 + 2]);
            acc[4 * k4 + 3] = fmaf(x, w.w, acc[4 * k4 + 3]);
        }
    }
    _Float16* opS = featS + ((size_t)b * FPIX + pb + t) * 64;
    #pragma unroll
    for (int k8 = 0; k8 < 8; k8++) {
        f16x8 v;
        #pragma unroll
        for (int e = 0; e < 8; e++) v[e] = (_Float16)acc[k8 * 8 + e];
        *(f16x8*)(opS + k8 * 8) = v;
    }
    _Float16* opH = featH + ((size_t)b * FPIX + pb + t) * 96;
    #pragma unroll
    for (int c8 = 0; c8 < 12; c8++) {
        f16x8 v;
        #pragma unroll
        for (int e = 0; e < 8; e++) v[e] = (_Float16)ld[(c8 * 8 + e) * 64 + t];
        *(f16x8*)(opH + c8 * 8) = v;
    }
}

// ---------------------------------------------------------------------------
// Lift: one thread per BEV cell, all 3 heights in-thread, no LDS/barriers.
// One-pass 96-ch weighted gather (single 192B write per pixel).
// ---------------------------------------------------------------------------
__global__ __launch_bounds__(256, 3) void k_lift(const _Float16* __restrict__ featS,
                                                 const _Float16* __restrict__ featH,
                                                 const float* __restrict__ l2i,
                                                 const float* __restrict__ dw1,
                                                 const float* __restrict__ db1,
                                                 const float* __restrict__ sw2,
                                                 const float* __restrict__ sb2,
                                                 const float* __restrict__ hW,
                                                 const float* __restrict__ baseT,
                                                 const float* __restrict__ wD,
                                                 const float* __restrict__ flagp,
                                                 _Float16* __restrict__ out) {
    const int tid = threadIdx.x;
    const int b = blockIdx.y;
    const int n = blockIdx.x * 256 + tid;
    const int i = n / BEV, j = n % BEV;
    const float px = ((j + 0.5f) / 320.0f) * 102.4f - 51.2f;
    const float py = ((i + 0.5f) / 320.0f) * 102.4f - 51.2f;
    const float* M = l2i + b * 16;
    const float m00 = M[0], m01 = M[1], m02 = M[2], m03 = M[3];
    const float m10 = M[4], m11 = M[5], m12 = M[6], m13 = M[7];
    const float m20 = M[8], m21 = M[9], m22 = M[10], m23 = M[11];

    const _Float16* fSb = featS + (size_t)b * FPIX * 64;
    const _Float16* fHb = featH + (size_t)b * FPIX * 96;

    int   ti[3][4];
    float tw[3][4];
    float logit[3];
    const bool fast = (flagp[0] != 0.f);

    #pragma unroll
    for (int h = 0; h < 3; h++) {
        logit[h] = -INFINITY;
        ti[h][0] = ti[h][1] = ti[h][2] = ti[h][3] = 0;
        tw[h][0] = tw[h][1] = tw[h][2] = tw[h][3] = 0.f;
        const float z = (float)h;
        const float p0 = m03 + m00 * px + m01 * py + m02 * z;
        const float p1 = m13 + m10 * px + m11 * py + m12 * z;
        const float dep = m23 + m20 * px + m21 * py + m22 * z;
        const float dv = fmaxf(dep, 1e-5f);
        const float u = p0 / dv, v = p1 / dv;
        const float gx = (u / 351.0f) * 2.0f - 1.0f;
        const float gy = (v / 127.0f) * 2.0f - 1.0f;
        const bool valid = (dep > 1e-3f) && (fabsf(gx) <= 1.0f) && (fabsf(gy) <= 1.0f);
        if (!valid) continue;

        float xs = (gx + 1.0f) * 0.5f * 351.0f;
        float ys = (gy + 1.0f) * 0.5f * 127.0f;
        float xf = floorf(xs), yf = floorf(ys);
        int x0 = (int)xf, y0 = (int)yf;
        float wx = xs - xf, wy = ys - yf;
        int x1 = (x0 < FEAT_W - 1) ? x0 + 1 : x0;
        int y1 = (y0 < FEAT_H - 1) ? y0 + 1 : y0;
        ti[h][0] = y0 * FEAT_W + x0;  ti[h][1] = y0 * FEAT_W + x1;
        ti[h][2] = y1 * FEAT_W + x0;  ti[h][3] = y1 * FEAT_W + x1;
        const float tw0 = (1.f - wx) * (1.f - wy), tw1 = wx * (1.f - wy);
        const float tw2 = (1.f - wx) * wy,         tw3 = wx * wy;
        tw[h][0] = tw0; tw[h][1] = tw1; tw[h][2] = tw2; tw[h][3] = tw3;

        const float dl = log1pf(fmaxf(dep, 1e-3f));
        const _Float16* q0 = fSb + (size_t)ti[h][0] * 64;
        const _Float16* q1 = fSb + (size_t)ti[h][1] * 64;
        const _Float16* q2 = fSb + (size_t)ti[h][2] * 64;
        const _Float16* q3 = fSb + (size_t)ti[h][3] * 64;
        float lg = sb2[0];
        if (fast) {
            #pragma unroll
            for (int kc = 0; kc < 4; kc++) {
                float hid[16];
                const float4* bs = (const float4*)(baseT + h * 64 + kc * 16);
                const float4* wd = (const float4*)(wD + kc * 16);
                #pragma unroll
                for (int q4 = 0; q4 < 4; q4++) {
                    float4 bv = bs[q4], wv = wd[q4];
                    hid[4 * q4 + 0] = fmaf(dl, wv.x, bv.x);
                    hid[4 * q4 + 1] = fmaf(dl, wv.y, bv.y);
                    hid[4 * q4 + 2] = fmaf(dl, wv.z, bv.z);
                    hid[4 * q4 + 3] = fmaf(dl, wv.w, bv.w);
                }
                f16x8 a0 = *(const f16x8*)(q0 + kc * 16),  a0b = *(const f16x8*)(q0 + kc * 16 + 8);
                f16x8 a1 = *(const f16x8*)(q1 + kc * 16),  a1b = *(const f16x8*)(q1 + kc * 16 + 8);
                f16x8 a2 = *(const f16x8*)(q2 + kc * 16),  a2b = *(const f16x8*)(q2 + kc * 16 + 8);
                f16x8 a3 = *(const f16x8*)(q3 + kc * 16),  a3b = *(const f16x8*)(q3 + kc * 16 + 8);
                #pragma unroll
                for (int e = 0; e < 8; e++) {
                    hid[e]     = fmaf(tw0, (float)a0[e],  fmaf(tw1, (float)a1[e],
                                 fmaf(tw2, (float)a2[e],  fmaf(tw3, (float)a3[e],  hid[e]))));
                    hid[e + 8] = fmaf(tw0, (float)a0b[e], fmaf(tw1, (float)a1b[e],
                                 fmaf(tw2, (float)a2b[e], fmaf(tw3, (float)a3b[e], hid[e + 8]))));
                }
                const float4* s2 = (const float4*)(sw2 + kc * 16);
                #pragma unroll
                for (int q4 = 0; q4 < 4; q4++) {
                    float4 sv = s2[q4];
                    lg = fmaf(fmaxf(hid[4 * q4 + 0], 0.f), sv.x, lg);
                    lg = fmaf(fmaxf(hid[4 * q4 + 1], 0.f), sv.y, lg);
                    lg = fmaf(fmaxf(hid[4 * q4 + 2], 0.f), sv.z, lg);
                    lg = fmaf(fmaxf(hid[4 * q4 + 3], 0.f), sv.w, lg);
                }
            }
        } else {
            #pragma unroll
            for (int kc = 0; kc < 4; kc++) {
                float hid[16];
                const float4* bs = (const float4*)(baseT + h * 64 + kc * 16);
                #pragma unroll
                for (int q4 = 0; q4 < 4; q4++) {
                    float4 bv = bs[q4];
                    hid[4 * q4 + 0] = bv.x; hid[4 * q4 + 1] = bv.y;
                    hid[4 * q4 + 2] = bv.z; hid[4 * q4 + 3] = bv.w;
                }
                f16x8 a0 = *(const f16x8*)(q0 + kc * 16),  a0b = *(const f16x8*)(q0 + kc * 16 + 8);
                f16x8 a1 = *(const f16x8*)(q1 + kc * 16),  a1b = *(const f16x8*)(q1 + kc * 16 + 8);
                f16x8 a2 = *(const f16x8*)(q2 + kc * 16),  a2b = *(const f16x8*)(q2 + kc * 16 + 8);
                f16x8 a3 = *(const f16x8*)(q3 + kc * 16),  a3b = *(const f16x8*)(q3 + kc * 16 + 8);
                #pragma unroll
                for (int e = 0; e < 8; e++) {
                    hid[e]     = fmaf(tw0, (float)a0[e],  fmaf(tw1, (float)a1[e],
                                 fmaf(tw2, (float)a2[e],  fmaf(tw3, (float)a3[e],  hid[e]))));
                    hid[e + 8] = fmaf(tw0, (float)a0b[e], fmaf(tw1, (float)a1b[e],
                                 fmaf(tw2, (float)a2b[e], fmaf(tw3, (float)a3b[e], hid[e + 8]))));
                }
                for (int jj = 0; jj < 64; jj++) {
                    float hd = fmaxf(fmaf(dl, dw1[jj], db1[jj]), 0.f);
                    const float4* hr = (const float4*)(hW + jj * 64 + kc * 16);
                    #pragma unroll
                    for (int q4 = 0; q4 < 4; q4++) {
                        float4 wv = hr[q4];
                        hid[4 * q4 + 0] = fmaf(hd, wv.x, hid[4 * q4 + 0]);
                        hid[4 * q4 + 1] = fmaf(hd, wv.y, hid[4 * q4 + 1]);
                        hid[4 * q4 + 2] = fmaf(hd, wv.z, hid[4 * q4 + 2]);
                        hid[4 * q4 + 3] = fmaf(hd, wv.w, hid[4 * q4 + 3]);
                    }
                }
                const float4* s2 = (const float4*)(sw2 + kc * 16);
                #pragma unroll
                for (int q4 = 0; q4 < 4; q4++) {
                    float4 sv = s2[q4];
                    lg = fmaf(fmaxf(hid[4 * q4 + 0], 0.f), sv.x, lg);
                    lg = fmaf(fmaxf(hid[4 * q4 + 1], 0.f), sv.y, lg);
                    lg = fmaf(fmaxf(hid[4 * q4 + 2], 0.f), sv.z, lg);
                    lg = fmaf(fmaxf(hid[4 * q4 + 3], 0.f), sv.w, lg);
                }
            }
        }
        logit[h] = lg;
    }

    const float mx = fmaxf(logit[0], fmaxf(logit[1], logit[2]));
    float wh[3] = {0.f, 0.f, 0.f};
    if (mx > -INFINITY) {
        float e0 = (logit[0] > -INFINITY) ? expf(logit[0] - mx) : 0.f;
        float e1 = (logit[1] > -INFINITY) ? expf(logit[1] - mx) : 0.f;
        float e2 = (logit[2] > -INFINITY) ? expf(logit[2] - mx) : 0.f;
        const float inv = 1.0f / (e0 + e1 + e2);
        wh[0] = e0 * inv; wh[1] = e1 * inv; wh[2] = e2 * inv;
    }

    float acc[96];
    #pragma unroll
    for (int k = 0; k < 96; k++) acc[k] = 0.f;
    #pragma unroll
    for (int h = 0; h < 3; h++) {
        if (wh[h] > 0.f) {
            const float c0 = wh[h] * tw[h][0], c1 = wh[h] * tw[h][1];
            const float c2 = wh[h] * tw[h][2], c3 = wh[h] * tw[h][3];
            const _Float16* g0 = fHb + (size_t)ti[h][0] * 96;
            const _Float16* g1 = fHb + (size_t)ti[h][1] * 96;
            const _Float16* g2 = fHb + (size_t)ti[h][2] * 96;
            const _Float16* g3 = fHb + (size_t)ti[h][3] * 96;
            #pragma unroll
            for (int c8 = 0; c8 < 12; c8++) {
                f16x8 v0 = *(const f16x8*)(g0 + c8 * 8);
                f16x8 v1 = *(const f16x8*)(g1 + c8 * 8);
                f16x8 v2 = *(const f16x8*)(g2 + c8 * 8);
                f16x8 v3 = *(const f16x8*)(g3 + c8 * 8);
                #pragma unroll
                for (int e = 0; e < 8; e++)
                    acc[c8 * 8 + e] += fmaf(c0, (float)v0[e], fmaf(c1, (float)v1[e],
                                       fmaf(c2, (float)v2[e], c3 * (float)v3[e])));
            }
        }
    }
    _Float16* op = out + ((size_t)(b * PD + i + 1) * PD + (j + 1)) * CH;
    #pragma unroll
    for (int c8 = 0; c8 < 12; ++c8) {
        f16x8 v;
        #pragma unroll
        for (int e = 0; e < 8; e++) v[e] = (_Float16)acc[c8 * 8 + e];
        *(f16x8*)(op + c8 * 8) = v;
    }
}

// ---------------------------------------------------------------------------
// Conv 3x3 + BN + ReLU, f16 MFMA implicit GEMM, explicit depth-2 pipeline
// (round-6 best-measured variant: no sched_group_barrier, no border folding).
// Block: 8 rows x 32 cols, 4 waves; wave = 4 pixel-tiles x 6 oc-tiles.
// A operand = weights (global, L2-hot), B = pixels (LDS halo tile).
// ---------------------------------------------------------------------------
#define LOAD_FRAGS(WF, PF, STEP) do {                                              \
    constexpr int _tap = (STEP) / 3, _kc = (STEP) % 3;                             \
    constexpr int _r = _tap / 3, _s = _tap % 3;                                    \
    _Pragma("unroll")                                                              \
    for (int ot = 0; ot < 6; ++ot)                                                 \
        WF[ot] = *(const f16x8*)(wtb + _tap * 9216 + ot * 1536 + _kc * 32);        \
    _Pragma("unroll")                                                              \
    for (int pt = 0; pt < 4; ++pt)                                                 \
        PF[pt] = *(const f16x8*)(&sA[((2 * w + (pt >> 1) + _r) * 34                \
                         + (pt & 1) * 16 + _s + n) * 104 + _kc * 32 + q * 8]);     \
} while (0)

#define DO_MFMA(WF, PF) do {                                                       \
    _Pragma("unroll")                                                              \
    for (int ot = 0; ot < 6; ++ot)                                                 \
        _Pragma("unroll")                                                          \
        for (int pt = 0; pt < 4; ++pt)                                             \
            acc[ot][pt] = __builtin_amdgcn_mfma_f32_16x16x32_f16(                  \
                              WF[ot], PF[pt], acc[ot][pt], 0, 0, 0);               \
} while (0)

#define TRIPLE(S)                                                                  \
    LOAD_FRAGS(wfc, pfc, (S) + 2); DO_MFMA(wfa, pfa);                              \
    LOAD_FRAGS(wfa, pfa, (S) + 3); DO_MFMA(wfb, pfb);                              \
    LOAD_FRAGS(wfb, pfb, (S) + 4); DO_MFMA(wfc, pfc);

template<int MODE>
__global__ __launch_bounds__(256, 2) void k_conv_mfma(
        const _Float16* __restrict__ in, const _Float16* __restrict__ wt,
        const float* __restrict__ bng, const float* __restrict__ bnb,
        const float* __restrict__ bnm, const float* __restrict__ bnv,
        void* __restrict__ outv) {
    __shared__ _Float16 sA[10 * 34 * 104];   // 70,720 B
    const int tid = threadIdx.x;
    const int w = tid >> 6, lane = tid & 63, q = lane >> 4, n = lane & 15;
    const int x0 = blockIdx.x * 32, y0 = blockIdx.y * 8, b = blockIdx.z;
    const _Float16* inb = in + (size_t)b * PPIX * CH;

    for (int idx = tid; idx < 10 * 34 * 12; idx += 256) {
        int pix = idx / 12, c8 = idx - pix * 12;
        int rr = pix / 34, cc = pix - rr * 34;
        *(f16x8*)(&sA[pix * 104 + c8 * 8]) =
            *(const f16x8*)(inb + ((size_t)(y0 + rr) * PD + (x0 + cc)) * CH + c8 * 8);
    }
    __syncthreads();

    f32x4 acc[6][4];
    #pragma unroll
    for (int ot = 0; ot < 6; ot++)
        #pragma unroll
        for (int pt = 0; pt < 4; pt++) acc[ot][pt] = (f32x4){0.f, 0.f, 0.f, 0.f};

    const _Float16* wtb = wt + n * CH + q * 8;

    f16x8 wfa[6], wfb[6], wfc[6], pfa[4], pfb[4], pfc[4];
    LOAD_FRAGS(wfa, pfa, 0);
    LOAD_FRAGS(wfb, pfb, 1);
    TRIPLE(0)  TRIPLE(3)  TRIPLE(6)  TRIPLE(9)
    TRIPLE(12) TRIPLE(15) TRIPLE(18) TRIPLE(21)
    LOAD_FRAGS(wfc, pfc, 26); DO_MFMA(wfa, pfa);   // step 24
    DO_MFMA(wfb, pfb);                              // step 25
    DO_MFMA(wfc, pfc);                              // step 26

    float scv[6][4], shv[6][4];
    #pragma unroll
    for (int ot = 0; ot < 6; ot++)
        #pragma unroll
        for (int rg = 0; rg < 4; rg++) {
            int oc = ot * 16 + q * 4 + rg;
            scv[ot][rg] = bng[oc] * rsqrtf(bnv[oc] + 1e-3f);
            shv[ot][rg] = fmaf(-bnm[oc], scv[ot][rg], bnb[oc]);
        }

    if (MODE == 0) {
        _Float16* outb = (_Float16*)outv + (size_t)b * PPIX * CH;
        #pragma unroll
        for (int pt = 0; pt < 4; pt++) {
            const int orow = y0 + 2 * w + (pt >> 1) + 1;
            const int ocol = x0 + (pt & 1) * 16 + n + 1;
            _Float16* op = outb + ((size_t)orow * PD + ocol) * CH + q * 4;
            #pragma unroll
            for (int ot = 0; ot < 6; ot++) {
                f16x4 pv;
                #pragma unroll
                for (int rg = 0; rg < 4; rg++)
                    pv[rg] = (_Float16)fmaxf(fmaf(acc[ot][pt][rg], scv[ot][rg], shv[ot][rg]), 0.f);
                *(f16x4*)(op + ot * 16) = pv;
            }
        }
    } else {
        float* outb = (float*)outv + (size_t)b * CH * NCELL;
        #pragma unroll
        for (int pt = 0; pt < 4; pt++) {
            const int prow = y0 + 2 * w + (pt >> 1);
            const int pcol = x0 + (pt & 1) * 16 + n;
            #pragma unroll
            for (int ot = 0; ot < 6; ot++)
                #pragma unroll
                for (int rg = 0; rg < 4; rg++) {
                    int oc = ot * 16 + q * 4 + rg;
                    outb[(size_t)oc * NCELL + prow * BEV + pcol] =
                        fmaxf(fmaf(acc[ot][pt][rg], scv[ot][rg], shv[ot][rg]), 0.f);
                }
        }
    }
}

// ---------------------------------------------------------------------------
extern "C" void kernel_launch(void* const* d_in, const int* in_sizes, int n_in,
                              void* d_out, int out_size, void* d_ws, size_t ws_size,
                              hipStream_t stream) {
    const float* feat = (const float*)d_in[0];
    const float* l2i  = (const float*)d_in[1];
    const float* he   = (const float*)d_in[2];
    const float* dw1  = (const float*)d_in[3];
    const float* db1  = (const float*)d_in[4];
    const float* dw2  = (const float*)d_in[5];
    const float* db2  = (const float*)d_in[6];
    const float* sw1  = (const float*)d_in[7];
    const float* sb1  = (const float*)d_in[8];
    const float* sw2  = (const float*)d_in[9];
    const float* sb2  = (const float*)d_in[10];
    const float* c1w  = (const float*)d_in[11];
    const float* bn1g = (const float*)d_in[12];
    const float* bn1b = (const float*)d_in[13];
    const float* bn1m = (const float*)d_in[14];
    const float* bn1v = (const float*)d_in[15];
    const float* c2w  = (const float*)d_in[16];
    const float* bn2g = (const float*)d_in[17];
    const float* bn2b = (const float*)d_in[18];
    const float* bn2m = (const float*)d_in[19];
    const float* bn2v = (const float*)d_in[20];

    float* ws = (float*)d_ws;
    _Float16*  bufB   = (_Float16*)(ws + OFF_BUFB);
    _Float16*  featS  = (_Float16*)(ws + OFF_FS);   // aliases bufB (dead before conv1)
    _Float16*  featH  = (_Float16*)(ws + OFF_FH);   // aliases bufB (dead before conv1)
    _Float16*  wtp    = (_Float16*)(ws + OFF_WT);
    float*     hW     = ws + OFF_HW;
    float*     baseT  = ws + OFF_BASE;
    float*     wD     = ws + OFF_WD;
    float*     flagp  = ws + OFF_FLAG;
    _Float16*  bufA   = (_Float16*)(ws + OFF_BUFA);
    _Float16*  wt1    = wtp;
    _Float16*  wt2    = wtp + 82944;

    hipLaunchKernelGGL(k_setup, dim3(660), dim3(256), 0, stream,
                       dw2, sw1, db2, he, sb1, dw1, db1, c1w, c2w,
                       hW, baseT, wD, flagp, wtp, bufA);
    hipLaunchKernelGGL(k_feats, dim3(FPIX / 64, 2), dim3(64), 0, stream,
                       feat, sw1, featS, featH);
    hipLaunchKernelGGL(k_lift, dim3(NCELL / 256, 2), dim3(256), 0, stream,
                       featS, featH, l2i, dw1, db1, sw2, sb2, hW, baseT, wD, flagp, bufA);
    // bufB borders only after k_lift (featS/featH alias bufB)
    hipLaunchKernelGGL(k_border, dim3(11), dim3(256), 0, stream, bufB);
    hipLaunchKernelGGL((k_conv_mfma<0>), dim3(10, 40, 2), dim3(256), 0, stream,
                       bufA, wt1, bn1g, bn1b, bn1m, bn1v, (void*)bufB);
    hipLaunchKernelGGL((k_conv_mfma<1>), dim3(10, 40, 2), dim3(256), 0, stream,
                       bufB, wt2, bn2g, bn2b, bn2m, bn2v, d_out);
}